// Round 10
// baseline (2632.220 us; speedup 1.0000x reference)
//
#include <hip/hip_runtime.h>

#define DIV_UP(a,b) (((a)+(b)-1)/(b))

typedef float v4f __attribute__((ext_vector_type(4)));
typedef unsigned short us4 __attribute__((ext_vector_type(4)));
typedef __attribute__((ext_vector_type(8))) short bf16x8;
typedef __attribute__((ext_vector_type(4))) float f32x4;

// ---------- non-temporal helpers ----------
__device__ __forceinline__ float4 ntload4(const float* p) {
  v4f v = __builtin_nontemporal_load((const v4f*)p);
  return make_float4(v.x, v.y, v.z, v.w);
}

// ---------- ordered-uint float max keys ----------
__device__ __forceinline__ unsigned f2key(float f) {
  unsigned u = __float_as_uint(f);
  return (u & 0x80000000u) ? ~u : (u | 0x80000000u);
}
__device__ __forceinline__ float key2f(unsigned u) {
  unsigned b = (u & 0x80000000u) ? (u ^ 0x80000000u) : ~u;
  return __uint_as_float(b);
}

// ---------- bf16 pack/unpack (RNE) ----------
__device__ __forceinline__ unsigned short f2bf(float f) {
  unsigned u = __float_as_uint(f);
  unsigned r = u + 0x7FFFu + ((u >> 16) & 1u);
  return (unsigned short)(r >> 16);
}
__device__ __forceinline__ float bf2f(unsigned short s) {
  return __uint_as_float(((unsigned)s) << 16);
}

// ---------- LDS XOR-swizzle (ushort units, 16B chunks) ----------
__device__ __forceinline__ int swz(int row) {
  return ((row ^ (row >> 3)) & 7) << 3;
}

// ---------- 3-kernel exclusive scan over cnt -> rowptr (+ dis in scan3) -----
__global__ void k_scan1(const int* __restrict__ cnt, int* __restrict__ incl,
                        int* __restrict__ bsum, int N) {
  __shared__ int s[1024];
  int t = threadIdx.x;
  int i = blockIdx.x * 1024 + t;
  int v = (i < N) ? cnt[i] : 0;
  s[t] = v;
  __syncthreads();
  for (int off = 1; off < 1024; off <<= 1) {
    int add = (t >= off) ? s[t - off] : 0;
    __syncthreads();
    s[t] += add;
    __syncthreads();
  }
  if (i < N) incl[i] = s[t];
  if (t == 1023) bsum[blockIdx.x] = s[1023];
}

__global__ void k_scan2(const int* __restrict__ bsum, int* __restrict__ bex, int nb) {
  __shared__ int s[128];
  int t = threadIdx.x;
  if (nb <= 128) {
    int v = (t < nb) ? bsum[t] : 0;
    s[t] = v;
    __syncthreads();
    for (int off = 1; off < 128; off <<= 1) {
      int add = (t >= off) ? s[t - off] : 0;
      __syncthreads();
      s[t] += add;
      __syncthreads();
    }
    if (t < nb) bex[t] = s[t] - v;  // exclusive
  } else if (t == 0) {
    int run = 0;
    for (int b = 0; b < nb; ++b) { bex[b] = run; run += bsum[b]; }
  }
}

// also zeroes the 8 work-steal counters each graph replay (runs before props)
__global__ void k_scan3(const int* __restrict__ incl, const int* __restrict__ cnt,
                        const int* __restrict__ bex, int* __restrict__ rowptr,
                        float* __restrict__ dis, int* __restrict__ pctr,
                        int N, int E) {
  int i = blockIdx.x * blockDim.x + threadIdx.x;
  if (i < N) {
    int c = cnt[i];
    rowptr[i] = incl[i] - c + bex[i >> 10];
    dis[i] = (c > 0) ? rsqrtf((float)c) : 0.0f;
  }
  if (i < 8) pctr[i] = 0;
  if (i == 0) rowptr[N] = E;
}

// ---------- shortcut GEMM body (MFMA): Sbf = bf16(x @ W_sc + b_sc) ----------
__device__ __forceinline__ void gemmsc_body(unsigned short* wTsc, unsigned short* x16,
                                            int bid,
                                            const float* __restrict__ X,
                                            const float* __restrict__ W,
                                            const float* __restrict__ bias,
                                            unsigned short* __restrict__ Sbf, int N) {
  int tid = threadIdx.x;
  for (int i4 = tid; i4 < 1024; i4 += 512) {
    int d = i4 >> 4, h4 = i4 & 15;
    float4 v = ((const float4*)W)[i4];
    int colb = h4 * 4;
    wTsc[(colb + 0) * 64 + (d ^ swz(colb + 0))] = f2bf(v.x);
    wTsc[(colb + 1) * 64 + (d ^ swz(colb + 1))] = f2bf(v.y);
    wTsc[(colb + 2) * 64 + (d ^ swz(colb + 2))] = f2bf(v.z);
    wTsc[(colb + 3) * 64 + (d ^ swz(colb + 3))] = f2bf(v.w);
  }
  int rowbase = bid * 128;
  for (int i4 = tid; i4 < 2048; i4 += 512) {
    int r = i4 >> 4, c4 = i4 & 15;
    int row = rowbase + r;
    float4 v = (row < N) ? ntload4(X + (size_t)row * 64 + c4 * 4)
                         : make_float4(0.f, 0.f, 0.f, 0.f);
    us4 pk;
    pk.x = f2bf(v.x); pk.y = f2bf(v.y); pk.z = f2bf(v.z); pk.w = f2bf(v.w);
    *(us4*)&x16[r * 64 + ((c4 * 4) ^ swz(r))] = pk;
  }
  __syncthreads();

  int lane = tid & 63;
  int wv = tid >> 6;
  int lo = lane & 15;
  int hi = lane >> 4;

  f32x4 acc[4];
#pragma unroll
  for (int ct = 0; ct < 4; ++ct) acc[ct] = (f32x4){0.f, 0.f, 0.f, 0.f};

#pragma unroll
  for (int ks = 0; ks < 2; ++ks) {
    int ar = wv * 16 + lo;
    bf16x8 af = *(const bf16x8*)&x16[ar * 64 + ((ks * 32 + hi * 8) ^ swz(ar))];
#pragma unroll
    for (int ct = 0; ct < 4; ++ct) {
      int br = ct * 16 + lo;
      bf16x8 bfr = *(const bf16x8*)&wTsc[br * 64 + ((ks * 32 + hi * 8) ^ swz(br))];
      acc[ct] = __builtin_amdgcn_mfma_f32_16x16x32_bf16(af, bfr, acc[ct], 0, 0, 0);
    }
  }

  float bv[4];
#pragma unroll
  for (int ct = 0; ct < 4; ++ct) bv[ct] = bias[ct * 16 + lo];
  int rowb = rowbase + wv * 16 + hi * 4;
#pragma unroll
  for (int reg = 0; reg < 4; ++reg) {
    int row = rowb + reg;
    if (row < N) {
      size_t o = (size_t)row * 64 + lo;
#pragma unroll
      for (int ct = 0; ct < 4; ++ct)
        __builtin_nontemporal_store(f2bf(acc[ct][reg] + bv[ct]), &Sbf[o + ct * 16]);
    }
  }
}

// ---------- shared MFMA tail for the 128x192 layer GEMM ---------------------
__device__ __forceinline__ void mfma192_tail(const unsigned short* x16,
                                             const unsigned short* wT,
                                             int rowbase, int tid,
                                             const float* __restrict__ bias,
                                             const float* __restrict__ dis,
                                             unsigned short* __restrict__ A02bf,
                                             unsigned short* __restrict__ Y1bf,
                                             unsigned short* __restrict__ Y2bf,
                                             int N) {
  int lane = tid & 63;
  int wv = tid >> 6;
  int lo = lane & 15;
  int hi = lane >> 4;

  f32x4 acc[12];
#pragma unroll
  for (int ct = 0; ct < 12; ++ct) acc[ct] = (f32x4){0.f, 0.f, 0.f, 0.f};

#pragma unroll
  for (int ks = 0; ks < 2; ++ks) {
    int ar = wv * 16 + lo;
    bf16x8 af = *(const bf16x8*)&x16[ar * 64 + ((ks * 32 + hi * 8) ^ swz(ar))];
#pragma unroll
    for (int ct = 0; ct < 12; ++ct) {
      int br = ct * 16 + lo;
      bf16x8 bfr = *(const bf16x8*)&wT[br * 64 + ((ks * 32 + hi * 8) ^ swz(br))];
      acc[ct] = __builtin_amdgcn_mfma_f32_16x16x32_bf16(af, bfr, acc[ct], 0, 0, 0);
    }
  }

  float bv[4];
#pragma unroll
  for (int ct = 0; ct < 4; ++ct) bv[ct] = bias[ct * 16 + lo];
  int rowb = rowbase + wv * 16 + hi * 4;
#pragma unroll
  for (int reg = 0; reg < 4; ++reg) {
    int row = rowb + reg;
    if (row < N) {
      float dn = dis[row];
      size_t o = (size_t)row * 64 + lo;
#pragma unroll
      for (int ct = 0; ct < 4; ++ct) {
        float o0 = acc[ct][reg] + bv[ct];
        float o1 = acc[ct + 4][reg];
        float o2 = acc[ct + 8][reg];
        A02bf[o + ct * 16] = f2bf(o0 - o2);
        Y1bf[o + ct * 16] = f2bf(o1);
        Y2bf[o + ct * 16] = f2bf(dn * o2);
      }
    }
  }
}

__device__ __forceinline__ void stage_wT(unsigned short* wT,
                                         const float* __restrict__ W, int tid) {
  for (int i4 = tid; i4 < 3072; i4 += 512) {
    int k3 = i4 >> 10, rem = i4 & 1023;
    int d = rem >> 4, h4 = rem & 15;
    float4 v = ((const float4*)W)[i4];
    int colb = k3 * 64 + h4 * 4;
    wT[(colb + 0) * 64 + (d ^ swz(colb + 0))] = f2bf(v.x);
    wT[(colb + 1) * 64 + (d ^ swz(colb + 1))] = f2bf(v.y);
    wT[(colb + 2) * 64 + (d ^ swz(colb + 2))] = f2bf(v.z);
    wT[(colb + 3) * 64 + (d ^ swz(colb + 3))] = f2bf(v.w);
  }
}

__device__ __forceinline__ void gemm192_l0_body(unsigned short* x16, unsigned short* wT,
                                                int bid,
                                                const float* __restrict__ X,
                                                const float* __restrict__ W,
                                                const float* __restrict__ bias,
                                                const float* __restrict__ dis,
                                                unsigned short* __restrict__ A02bf,
                                                unsigned short* __restrict__ Y1bf,
                                                unsigned short* __restrict__ Y2bf,
                                                int N) {
  int tid = threadIdx.x;
  stage_wT(wT, W, tid);
  int rowbase = bid * 128;
  for (int i4 = tid; i4 < 2048; i4 += 512) {
    int r = i4 >> 4, c4 = i4 & 15;
    int row = rowbase + r;
    float4 v = (row < N) ? ntload4(X + (size_t)row * 64 + c4 * 4)
                         : make_float4(0.f, 0.f, 0.f, 0.f);
    us4 pk;
    pk.x = f2bf(v.x); pk.y = f2bf(v.y); pk.z = f2bf(v.z); pk.w = f2bf(v.w);
    *(us4*)&x16[r * 64 + ((c4 * 4) ^ swz(r))] = pk;
  }
  __syncthreads();
  mfma192_tail(x16, wT, rowbase, tid, bias, dis, A02bf, Y1bf, Y2bf, N);
}

// ---------- fused A: gemmsc | count+slot | sentinel | poolinit --------------
// Count role records eslot[e] = within-row slot (atomic return). 1.6M atomics
// at the measured ~8/cycle device atomic ceiling => ~84us floor for this role.
__global__ __launch_bounds__(512) void k_fused_a(const float* __restrict__ X,
                                                 const float* __restrict__ W,
                                                 const float* __restrict__ bias,
                                                 unsigned short* __restrict__ Sbf,
                                                 const int* __restrict__ row,
                                                 int* __restrict__ cnt,
                                                 int* __restrict__ eslot,
                                                 unsigned short* __restrict__ Y2bf,
                                                 unsigned short* __restrict__ Vbf,
                                                 unsigned* __restrict__ pooled,
                                                 int N, int E, int NBG, int NC,
                                                 int npool, int q) {
  __shared__ unsigned short wTsc[64 * 64];   // 8 KB
  __shared__ unsigned short x16a[128 * 64];  // 16 KB
  int bid = blockIdx.x;
  bool isg = (bid % q == 0) && (bid / q < NBG);
  if (isg) {
    gemmsc_body(wTsc, x16a, bid / q, X, W, bias, Sbf, N);
  } else {
    int before = min((bid + q - 1) / q, NBG);
    int oi = bid - before;
    if (oi < NC) {
      int e0 = oi * 2048 + threadIdx.x;
      int r[4], idx[4];
#pragma unroll
      for (int k = 0; k < 4; ++k) {
        int e = e0 + k * 512;
        if (e < E) r[k] = row[e];
      }
#pragma unroll
      for (int k = 0; k < 4; ++k) {
        int e = e0 + k * 512;
        if (e < E) idx[k] = atomicAdd(&cnt[r[k]], 1);
      }
#pragma unroll
      for (int k = 0; k < 4; ++k) {
        int e = e0 + k * 512;
        if (e < E) __builtin_nontemporal_store(idx[k], &eslot[e]);
      }
    } else if (oi == NC) {
      if (threadIdx.x < 64) {
        Y2bf[(size_t)N * 64 + threadIdx.x] = 0;
        Vbf[(size_t)N * 64 + threadIdx.x] = 0;
      }
    } else {
      int i = (oi - NC - 1) * 512 + threadIdx.x;
      if (i < npool) pooled[i] = 0x007FFFFFu;  // key(-inf)
    }
  }
}

// ---------- fused B: gemm192(l0, MFMA) | atomic-free fill ------------------
__global__ __launch_bounds__(512) void k_fused_b(const float* __restrict__ X,
                                                 const float* __restrict__ W,
                                                 const float* __restrict__ bias,
                                                 const float* __restrict__ dis,
                                                 unsigned short* __restrict__ A02bf,
                                                 unsigned short* __restrict__ Y1bf,
                                                 unsigned short* __restrict__ Y2bf,
                                                 const int* __restrict__ row,
                                                 const int* __restrict__ col,
                                                 const int* __restrict__ rowptr,
                                                 const int* __restrict__ eslot,
                                                 int* __restrict__ ccol,
                                                 int N, int E, int NBG, int q) {
  __shared__ unsigned short x16b[128 * 64];  // 16 KB
  __shared__ unsigned short wTb[192 * 64];   // 24 KB
  int bid = blockIdx.x;
  bool isg = (bid % q == 0) && (bid / q < NBG);
  if (isg) {
    gemm192_l0_body(x16b, wTb, bid / q, X, W, bias, dis, A02bf, Y1bf, Y2bf, N);
  } else {
    int before = min((bid + q - 1) / q, NBG);
    int oi = bid - before;
    int e0 = oi * 2048 + threadIdx.x;
    int r[4], c[4], sl[4], base[4];
#pragma unroll
    for (int k = 0; k < 4; ++k) {
      int e = e0 + k * 512;
      if (e < E) { r[k] = row[e]; c[k] = col[e]; sl[k] = eslot[e]; }
    }
#pragma unroll
    for (int k = 0; k < 4; ++k) {
      int e = e0 + k * 512;
      if (e < E) base[k] = rowptr[r[k]];
    }
#pragma unroll
    for (int k = 0; k < 4; ++k) {
      int e = e0 + k * 512;
      if (e < E) ccol[base[k] + sl[k]] = c[k];
    }
  }
}

// ---------- layer GEMM (l>=1): MFMA, bf16 input + in-block BN ---------------
__global__ __launch_bounds__(512) void k_gemm192(
    const unsigned short* __restrict__ Cbf,
    const float* __restrict__ sums, const float* __restrict__ sumsq,
    const float* __restrict__ g, const float* __restrict__ be,
    const float* __restrict__ W, const float* __restrict__ bias,
    const float* __restrict__ dis,
    unsigned short* __restrict__ A02bf, unsigned short* __restrict__ Y1bf,
    unsigned short* __restrict__ Y2bf, int N) {
  __shared__ unsigned short x16[128 * 64];
  __shared__ unsigned short wT[192 * 64];
  int bid = blockIdx.x;
  int tid = threadIdx.x;

  int cb = (tid & 15) * 4;
  float inv_n = 1.0f / (float)N;
  float scv[4], shv[4];
#pragma unroll
  for (int k = 0; k < 4; ++k) {
    float mu = sums[cb + k] * inv_n;
    float var = sumsq[cb + k] * inv_n - mu * mu;
    float sc = g[cb + k] * rsqrtf(var + 1e-5f);
    scv[k] = sc;
    shv[k] = be[cb + k] - mu * sc;
  }

  stage_wT(wT, W, tid);

  int rowbase = bid * 128;
  for (int i4 = tid; i4 < 2048; i4 += 512) {
    int r = i4 >> 4, c4 = i4 & 15;
    int row = rowbase + r;
    float vx, vy, vz, vw;
    if (row < N) {
      unsigned long long u =
          *(const unsigned long long*)(Cbf + (size_t)row * 64 + c4 * 4);
      vx = bf2f((unsigned short)(u & 0xffffu));
      vy = bf2f((unsigned short)((u >> 16) & 0xffffu));
      vz = bf2f((unsigned short)((u >> 32) & 0xffffu));
      vw = bf2f((unsigned short)(u >> 48));
    } else {
      vx = vy = vz = vw = 0.f;
    }
    float a = vx * scv[0] + shv[0];
    float b = vy * scv[1] + shv[1];
    float c = vz * scv[2] + shv[2];
    float d = vw * scv[3] + shv[3];
    a = (a > 0.f) ? a : 0.01f * a;
    b = (b > 0.f) ? b : 0.01f * b;
    c = (c > 0.f) ? c : 0.01f * c;
    d = (d > 0.f) ? d : 0.01f * d;
    us4 pk;
    pk.x = f2bf(a); pk.y = f2bf(b); pk.z = f2bf(c); pk.w = f2bf(d);
    *(us4*)&x16[r * 64 + ((c4 * 4) ^ swz(r))] = pk;
  }
  __syncthreads();

  mfma192_tail(x16, wT, rowbase, tid, bias, dis, A02bf, Y1bf, Y2bf, N);
}

// ---------- prop v11: v8 quartet core + dynamic contiguous chunks ----------
// Round-8/9 established: per-pass FETCH ~90MB = 8 XCDs x zbf(12.8MB) is the
// irreducible private-L2 broadcast floor; MLP widening (v10) and chunking
// (v9) are null/negative. Remaining lever: load balance + stream locality.
// Lane 0 of each wave grabs CH=4 CONTIGUOUS rows via global counter
// (~25K atomics, trivial): erases the Poisson slow-tail over 8192 static
// waves, and makes rowptr/ccol/inA/out per-wave sequential (static stride
// was 8192 rows -> zero line reuse on every non-gather stream).
// Per 16-col window: lanes 0-15 load ccol, shfl broadcast; quartet
// dwordx2 gathers (4 rows / 512B per instr). Merge via shfl_xor(16,32).
// MODE 1: Vbf[n] = bf16( dis[n]*(Y1[n] - 2*dis[n]*acc) ); zeroes stats
// MODE 2: Cbf[n] = bf16( A02[n] - dis[n]*acc )  (+ fused BN stats)
__device__ __forceinline__ void gather4(int cw, int qtr, int s,
                                        const unsigned long long* z64, float* a) {
#pragma unroll
  for (int u = 0; u < 4; ++u) {
    int c = __shfl(cw, 4 * u + qtr, 64);  // quarter q gets col 4u+q
    unsigned long long zv = z64[(size_t)c * 16 + s];
    unsigned d0 = (unsigned)zv, d1 = (unsigned)(zv >> 32);
    a[0] += __uint_as_float(d0 << 16);
    a[1] += __uint_as_float(d0 & 0xFFFF0000u);
    a[2] += __uint_as_float(d1 << 16);
    a[3] += __uint_as_float(d1 & 0xFFFF0000u);
  }
}

template <int MODE>
__global__ __launch_bounds__(256) void k_prop4(const int* __restrict__ rowptr,
                                               const int* __restrict__ ccol,
                                               const float* __restrict__ dis,
                                               const unsigned short* __restrict__ zbf,
                                               const unsigned short* __restrict__ inAbf,
                                               unsigned short* __restrict__ outbf,
                                               float* __restrict__ sums,
                                               float* __restrict__ sumsq,
                                               float* __restrict__ zstats,
                                               int* __restrict__ ctr, int N) {
  if (MODE == 1 && blockIdx.x == 0 && threadIdx.x < 128) zstats[threadIdx.x] = 0.f;
  int lane = threadIdx.x & 63;
  int wid = threadIdx.x >> 6;
  int qtr = lane >> 4;  // quarter 0..3: handles neighbor indices 4u+qtr
  int s = lane & 15;    // sub-lane: owns channels 4s..4s+3 (8 B of a row)
  const unsigned long long* z64 = (const unsigned long long*)zbf;
  const unsigned long long* inA64 = (const unsigned long long*)inAbf;
  unsigned long long* out64 = (unsigned long long*)outbf;
  float st[4] = {0.f, 0.f, 0.f, 0.f}, st2[4] = {0.f, 0.f, 0.f, 0.f};

  const int CH = 4;  // contiguous rows per grab
  for (;;) {
    int base = 0;
    if (lane == 0) base = atomicAdd(ctr, CH);
    base = __shfl(base, 0, 64);
    if (base >= N) break;
    int nend = min(base + CH, N);
    for (int n = base; n < nend; ++n) {
      int beg = rowptr[n], end = rowptr[n + 1];  // contiguous -> L2-hot
      float dn = dis[n];                          // hoisted above gathers
      size_t o = (size_t)n * 16 + s;
      unsigned long long av = 0;
      if (qtr == 0) av = inA64[o];                // hoisted above gathers
      float a[4] = {0.f, 0.f, 0.f, 0.f};
      for (int j = beg; j < end; j += 16) {
        int jj = j + s;
        int cl = ccol[jj];          // ccol padded by 64 -> safe load
        cl = (jj < end) ? cl : N;   // sentinel row N is zeroed
        gather4(cl, qtr, s, z64, a);
      }
      // merge quarter partials: every lane ends with the full neighbor sum
#pragma unroll
      for (int k = 0; k < 4; ++k) {
        a[k] += __shfl_xor(a[k], 16, 64);
        a[k] += __shfl_xor(a[k], 32, 64);
      }
      if (qtr == 0) {
        unsigned b0 = (unsigned)av, b1 = (unsigned)(av >> 32);
        float x0 = __uint_as_float(b0 << 16);
        float x1 = __uint_as_float(b0 & 0xFFFF0000u);
        float x2 = __uint_as_float(b1 << 16);
        float x3 = __uint_as_float(b1 & 0xFFFF0000u);
        if (MODE == 1) {
          float v0 = dn * (x0 - 2.f * dn * a[0]);
          float v1 = dn * (x1 - 2.f * dn * a[1]);
          float v2 = dn * (x2 - 2.f * dn * a[2]);
          float v3 = dn * (x3 - 2.f * dn * a[3]);
          unsigned lo = (unsigned)f2bf(v0) | ((unsigned)f2bf(v1) << 16);
          unsigned hi = (unsigned)f2bf(v2) | ((unsigned)f2bf(v3) << 16);
          out64[o] = (unsigned long long)lo | ((unsigned long long)hi << 32);
        } else {
          float v0 = x0 - dn * a[0];
          float v1 = x1 - dn * a[1];
          float v2 = x2 - dn * a[2];
          float v3 = x3 - dn * a[3];
          unsigned lo = (unsigned)f2bf(v0) | ((unsigned)f2bf(v1) << 16);
          unsigned hi = (unsigned)f2bf(v2) | ((unsigned)f2bf(v3) << 16);
          out64[o] = (unsigned long long)lo | ((unsigned long long)hi << 32);
          st[0] += v0; st2[0] = fmaf(v0, v0, st2[0]);
          st[1] += v1; st2[1] = fmaf(v1, v1, st2[1]);
          st[2] += v2; st2[2] = fmaf(v2, v2, st2[2]);
          st[3] += v3; st2[3] = fmaf(v3, v3, st2[3]);
        }
      }
    }
  }
  if (MODE == 2) {
    __shared__ float red[2][4][64];
    if (qtr == 0) {
#pragma unroll
      for (int k = 0; k < 4; ++k) {
        red[0][wid][4 * s + k] = st[k];
        red[1][wid][4 * s + k] = st2[k];
      }
    }
    __syncthreads();
    if (wid == 0) {
      float a = red[0][0][lane] + red[0][1][lane] + red[0][2][lane] + red[0][3][lane];
      float b = red[1][0][lane] + red[1][1][lane] + red[1][2][lane] + red[1][3][lane];
      atomicAdd(&sums[lane], a);
      atomicAdd(&sumsq[lane], b);
    }
  }
}

// fused: h = lrelu(bn(Cbf)) + Sbf; segment-max into pooled (coefs in-block)
__global__ void k_bnpool(const unsigned short* __restrict__ Cbf,
                         const float* __restrict__ sums, const float* __restrict__ sumsq,
                         const float* __restrict__ g, const float* __restrict__ be,
                         const unsigned short* __restrict__ Sbf,
                         const int* __restrict__ batch,
                         unsigned* __restrict__ pooled, int N) {
  __shared__ float sc_s[64], sh_s[64];
  if (threadIdx.x < 64) {
    int h = threadIdx.x;
    float inv_n = 1.0f / (float)N;
    float mu = sums[h] * inv_n;
    float var = sumsq[h] * inv_n - mu * mu;
    float sc = g[h] * rsqrtf(var + 1e-5f);
    sc_s[h] = sc;
    sh_s[h] = be[h] - mu * sc;
  }
  __syncthreads();
  int t = threadIdx.x;
  int h = t & 63;
  int rsub = t >> 6;
  int base = blockIdx.x * 64;
  float sc = sc_s[h], sh = sh_s[h];
  int cur_g = -1;
  unsigned best = 0;
  for (int i = 0; i < 16; ++i) {
    int n = base + rsub + 4 * i;
    if (n >= N) break;
    int gidx = batch[n];
    size_t o = (size_t)n * 64 + h;
    float a = bf2f(__builtin_nontemporal_load(&Cbf[o])) * sc + sh;
    a = (a > 0.f) ? a : 0.01f * a;
    a += bf2f(__builtin_nontemporal_load(&Sbf[o]));
    unsigned k = f2key(a);
    if (gidx != cur_g) {
      if (cur_g >= 0) atomicMax(&pooled[cur_g * 64 + h], best);
      cur_g = gidx;
      best = k;
    } else {
      best = max(best, k);
    }
  }
  if (cur_g >= 0) atomicMax(&pooled[cur_g * 64 + h], best);
}

__global__ void k_final(const unsigned* __restrict__ pooled, const float* __restrict__ w_lin,
                        const float* __restrict__ b_lin, float* __restrict__ out) {
  int g = blockIdx.x;
  int h = threadIdx.x;
  float v = key2f(pooled[g * 64 + h]) * w_lin[h];
  for (int off = 32; off > 0; off >>= 1) v += __shfl_down(v, off, 64);
  if (h == 0) out[g] = v + b_lin[0];
}

extern "C" void kernel_launch(void* const* d_in, const int* in_sizes, int n_in,
                              void* d_out, int out_size, void* d_ws, size_t ws_size,
                              hipStream_t stream) {
  const float* x = (const float*)d_in[0];
  const int* ei = (const int*)d_in[1];
  const int* batch = (const int*)d_in[2];
  const float* w1 = (const float*)d_in[3];
  const float* b1 = (const float*)d_in[4];
  const float* w2 = (const float*)d_in[5];
  const float* b2 = (const float*)d_in[6];
  const float* w3 = (const float*)d_in[7];
  const float* b3 = (const float*)d_in[8];
  const float* g1 = (const float*)d_in[9];
  const float* be1 = (const float*)d_in[10];
  const float* g2 = (const float*)d_in[11];
  const float* be2 = (const float*)d_in[12];
  const float* g3 = (const float*)d_in[13];
  const float* be3 = (const float*)d_in[14];
  const float* w_sc = (const float*)d_in[15];
  const float* b_sc = (const float*)d_in[16];
  const float* w_lin = (const float*)d_in[17];
  const float* b_lin = (const float*)d_in[18];

  int N = in_sizes[0] / 64;
  int E = in_sizes[1] / 2;
  int G = out_size;
  const int* row = ei;
  const int* col = ei + E;

  char* p = (char*)d_ws;
  auto carve = [&](size_t bytes) -> void* {
    void* r = (void*)p;
    p += (bytes + 255) & ~(size_t)255;
    return r;
  };
  int* cnt = (int*)carve((size_t)N * 4);
  float* dis = (float*)carve((size_t)N * 4);
  int* rowptr = (int*)carve((size_t)(N + 1) * 4);
  int* eslot = (int*)carve((size_t)E * 4);
  int* incl = (int*)carve((size_t)N * 4);
  int* bsum = (int*)carve(1024);
  int* bex = (int*)carve(1024);
  int* pctr = (int*)carve(256);            // 8 work-steal counters (scan3 zeroes)
  int* ccol = (int*)carve((size_t)(E + 64) * 4);   // +64 pad for window over-read
  unsigned short* Sbf = (unsigned short*)carve((size_t)N * 64 * 2);
  unsigned short* A02bf = (unsigned short*)carve((size_t)N * 64 * 2);
  unsigned short* Y1bf = (unsigned short*)carve((size_t)N * 64 * 2);
  unsigned short* Y2bf = (unsigned short*)carve((size_t)(N + 1) * 64 * 2);  // row N = 0
  unsigned short* Vbf = (unsigned short*)carve((size_t)(N + 1) * 64 * 2);   // row N = 0
  unsigned short* Cbf = (unsigned short*)carve((size_t)N * 64 * 2);
  float* stats = (float*)carve(256 * 4);  // sums|sumsq
  unsigned* pooled = (unsigned*)carve((size_t)G * 64 * 4);

  int NBG = DIV_UP(N, 128);
  int NC = DIV_UP(E, 2048);
  int npool = G * 64;
  int NPI = DIV_UP(npool, 512);

  int TA = NBG + NC + 1 + NPI;
  int qa = (NBG > 1) ? (TA - 1) / (NBG - 1) : 1;
  if (qa < 1) qa = 1;
  int TB = NBG + NC;
  int qb = (NBG > 1) ? (TB - 1) / (NBG - 1) : 1;
  if (qb < 1) qb = 1;

  // ---- graph build + overlapped independent compute ----
  hipMemsetAsync(cnt, 0, (size_t)N * 4, stream);
  // A: gemmsc || degree count+slot || sentinel zero || poolinit
  k_fused_a<<<TA, 512, 0, stream>>>(x, w_sc, b_sc, Sbf, row, cnt, eslot,
                                    Y2bf, Vbf, pooled, N, E, NBG, NC, npool, qa);
  int nb = DIV_UP(N, 1024);
  k_scan1<<<nb, 1024, 0, stream>>>(cnt, incl, bsum, N);
  k_scan2<<<1, 128, 0, stream>>>(bsum, bex, nb);
  k_scan3<<<DIV_UP(N, 256), 256, 0, stream>>>(incl, cnt, bex, rowptr, dis, pctr,
                                              N, E);
  // B: gemm192(layer0) || atomic-free CSR fill
  k_fused_b<<<TB, 512, 0, stream>>>(x, w1, b1, dis, A02bf, Y1bf, Y2bf,
                                    row, col, rowptr, eslot, ccol, N, E, NBG, qb);

  const float* Ws[3] = {w1, w2, w3};
  const float* bs[3] = {b1, b2, b3};
  const float* gs[3] = {g1, g2, g3};
  const float* bes[3] = {be1, be2, be3};

  const int PBLK = 2048;      // persistent blocks, 4 waves each (all resident)
  for (int l = 0; l < 3; ++l) {
    if (l > 0)
      k_gemm192<<<NBG, 512, 0, stream>>>(Cbf, stats, stats + 64, gs[l - 1], bes[l - 1],
                                         Ws[l], bs[l], dis, A02bf, Y1bf, Y2bf, N);
    // Vbf = bf16( dis * (Y1 + 2*P*Y2) )   (also zeroes stats)
    k_prop4<1><<<PBLK, 256, 0, stream>>>(rowptr, ccol, dis, Y2bf, Y1bf,
                                         Vbf, nullptr, nullptr, stats,
                                         pctr + 2 * l, N);
    // Cbf = bf16( (Y0 - Y2) + P*V )  (+ fused BN stats)
    k_prop4<2><<<PBLK, 256, 0, stream>>>(rowptr, ccol, dis, Vbf, A02bf,
                                         Cbf, stats, stats + 64, nullptr,
                                         pctr + 2 * l + 1, N);
  }

  k_bnpool<<<DIV_UP(N, 64), 256, 0, stream>>>(Cbf, stats, stats + 64, g3, be3,
                                              Sbf, batch, pooled, N);
  k_final<<<G, 64, 0, stream>>>(pooled, w_lin, b_lin, (float*)d_out);
}

// Round 11
// 617.697 us; speedup vs baseline: 4.2613x; 4.2613x over previous
//
#include <hip/hip_runtime.h>

#define DIV_UP(a,b) (((a)+(b)-1)/(b))

typedef float v4f __attribute__((ext_vector_type(4)));
typedef unsigned short us4 __attribute__((ext_vector_type(4)));
typedef __attribute__((ext_vector_type(8))) short bf16x8;
typedef __attribute__((ext_vector_type(4))) float f32x4;

// ---------- non-temporal helpers ----------
__device__ __forceinline__ float4 ntload4(const float* p) {
  v4f v = __builtin_nontemporal_load((const v4f*)p);
  return make_float4(v.x, v.y, v.z, v.w);
}

// ---------- ordered-uint float max keys ----------
__device__ __forceinline__ unsigned f2key(float f) {
  unsigned u = __float_as_uint(f);
  return (u & 0x80000000u) ? ~u : (u | 0x80000000u);
}
__device__ __forceinline__ float key2f(unsigned u) {
  unsigned b = (u & 0x80000000u) ? (u ^ 0x80000000u) : ~u;
  return __uint_as_float(b);
}

// ---------- bf16 pack/unpack (RNE) ----------
__device__ __forceinline__ unsigned short f2bf(float f) {
  unsigned u = __float_as_uint(f);
  unsigned r = u + 0x7FFFu + ((u >> 16) & 1u);
  return (unsigned short)(r >> 16);
}
__device__ __forceinline__ float bf2f(unsigned short s) {
  return __uint_as_float(((unsigned)s) << 16);
}

// ---------- LDS XOR-swizzle (ushort units, 16B chunks) ----------
__device__ __forceinline__ int swz(int row) {
  return ((row ^ (row >> 3)) & 7) << 3;
}

// ---------- 3-kernel exclusive scan over cnt -> rowptr (+ dis in scan3) -----
__global__ void k_scan1(const int* __restrict__ cnt, int* __restrict__ incl,
                        int* __restrict__ bsum, int N) {
  __shared__ int s[1024];
  int t = threadIdx.x;
  int i = blockIdx.x * 1024 + t;
  int v = (i < N) ? cnt[i] : 0;
  s[t] = v;
  __syncthreads();
  for (int off = 1; off < 1024; off <<= 1) {
    int add = (t >= off) ? s[t - off] : 0;
    __syncthreads();
    s[t] += add;
    __syncthreads();
  }
  if (i < N) incl[i] = s[t];
  if (t == 1023) bsum[blockIdx.x] = s[1023];
}

__global__ void k_scan2(const int* __restrict__ bsum, int* __restrict__ bex, int nb) {
  __shared__ int s[128];
  int t = threadIdx.x;
  if (nb <= 128) {
    int v = (t < nb) ? bsum[t] : 0;
    s[t] = v;
    __syncthreads();
    for (int off = 1; off < 128; off <<= 1) {
      int add = (t >= off) ? s[t - off] : 0;
      __syncthreads();
      s[t] += add;
      __syncthreads();
    }
    if (t < nb) bex[t] = s[t] - v;  // exclusive
  } else if (t == 0) {
    int run = 0;
    for (int b = 0; b < nb; ++b) { bex[b] = run; run += bsum[b]; }
  }
}

__global__ void k_scan3(const int* __restrict__ incl, const int* __restrict__ cnt,
                        const int* __restrict__ bex, int* __restrict__ rowptr,
                        float* __restrict__ dis, int N, int E) {
  int i = blockIdx.x * blockDim.x + threadIdx.x;
  if (i < N) {
    int c = cnt[i];
    rowptr[i] = incl[i] - c + bex[i >> 10];
    dis[i] = (c > 0) ? rsqrtf((float)c) : 0.0f;
  }
  if (i == 0) rowptr[N] = E;
}

// ---------- shortcut GEMM body (MFMA): Sbf = bf16(x @ W_sc + b_sc) ----------
__device__ __forceinline__ void gemmsc_body(unsigned short* wTsc, unsigned short* x16,
                                            int bid,
                                            const float* __restrict__ X,
                                            const float* __restrict__ W,
                                            const float* __restrict__ bias,
                                            unsigned short* __restrict__ Sbf, int N) {
  int tid = threadIdx.x;
  for (int i4 = tid; i4 < 1024; i4 += 512) {
    int d = i4 >> 4, h4 = i4 & 15;
    float4 v = ((const float4*)W)[i4];
    int colb = h4 * 4;
    wTsc[(colb + 0) * 64 + (d ^ swz(colb + 0))] = f2bf(v.x);
    wTsc[(colb + 1) * 64 + (d ^ swz(colb + 1))] = f2bf(v.y);
    wTsc[(colb + 2) * 64 + (d ^ swz(colb + 2))] = f2bf(v.z);
    wTsc[(colb + 3) * 64 + (d ^ swz(colb + 3))] = f2bf(v.w);
  }
  int rowbase = bid * 128;
  for (int i4 = tid; i4 < 2048; i4 += 512) {
    int r = i4 >> 4, c4 = i4 & 15;
    int row = rowbase + r;
    float4 v = (row < N) ? ntload4(X + (size_t)row * 64 + c4 * 4)
                         : make_float4(0.f, 0.f, 0.f, 0.f);
    us4 pk;
    pk.x = f2bf(v.x); pk.y = f2bf(v.y); pk.z = f2bf(v.z); pk.w = f2bf(v.w);
    *(us4*)&x16[r * 64 + ((c4 * 4) ^ swz(r))] = pk;
  }
  __syncthreads();

  int lane = tid & 63;
  int wv = tid >> 6;
  int lo = lane & 15;
  int hi = lane >> 4;

  f32x4 acc[4];
#pragma unroll
  for (int ct = 0; ct < 4; ++ct) acc[ct] = (f32x4){0.f, 0.f, 0.f, 0.f};

#pragma unroll
  for (int ks = 0; ks < 2; ++ks) {
    int ar = wv * 16 + lo;
    bf16x8 af = *(const bf16x8*)&x16[ar * 64 + ((ks * 32 + hi * 8) ^ swz(ar))];
#pragma unroll
    for (int ct = 0; ct < 4; ++ct) {
      int br = ct * 16 + lo;
      bf16x8 bfr = *(const bf16x8*)&wTsc[br * 64 + ((ks * 32 + hi * 8) ^ swz(br))];
      acc[ct] = __builtin_amdgcn_mfma_f32_16x16x32_bf16(af, bfr, acc[ct], 0, 0, 0);
    }
  }

  float bv[4];
#pragma unroll
  for (int ct = 0; ct < 4; ++ct) bv[ct] = bias[ct * 16 + lo];
  int rowb = rowbase + wv * 16 + hi * 4;
#pragma unroll
  for (int reg = 0; reg < 4; ++reg) {
    int row = rowb + reg;
    if (row < N) {
      size_t o = (size_t)row * 64 + lo;
#pragma unroll
      for (int ct = 0; ct < 4; ++ct)
        __builtin_nontemporal_store(f2bf(acc[ct][reg] + bv[ct]), &Sbf[o + ct * 16]);
    }
  }
}

// ---------- shared MFMA tail for the 128x192 layer GEMM ---------------------
__device__ __forceinline__ void mfma192_tail(const unsigned short* x16,
                                             const unsigned short* wT,
                                             int rowbase, int tid,
                                             const float* __restrict__ bias,
                                             const float* __restrict__ dis,
                                             unsigned short* __restrict__ A02bf,
                                             unsigned short* __restrict__ Y1bf,
                                             unsigned short* __restrict__ Y2bf,
                                             int N) {
  int lane = tid & 63;
  int wv = tid >> 6;
  int lo = lane & 15;
  int hi = lane >> 4;

  f32x4 acc[12];
#pragma unroll
  for (int ct = 0; ct < 12; ++ct) acc[ct] = (f32x4){0.f, 0.f, 0.f, 0.f};

#pragma unroll
  for (int ks = 0; ks < 2; ++ks) {
    int ar = wv * 16 + lo;
    bf16x8 af = *(const bf16x8*)&x16[ar * 64 + ((ks * 32 + hi * 8) ^ swz(ar))];
#pragma unroll
    for (int ct = 0; ct < 12; ++ct) {
      int br = ct * 16 + lo;
      bf16x8 bfr = *(const bf16x8*)&wT[br * 64 + ((ks * 32 + hi * 8) ^ swz(br))];
      acc[ct] = __builtin_amdgcn_mfma_f32_16x16x32_bf16(af, bfr, acc[ct], 0, 0, 0);
    }
  }

  float bv[4];
#pragma unroll
  for (int ct = 0; ct < 4; ++ct) bv[ct] = bias[ct * 16 + lo];
  int rowb = rowbase + wv * 16 + hi * 4;
#pragma unroll
  for (int reg = 0; reg < 4; ++reg) {
    int row = rowb + reg;
    if (row < N) {
      float dn = dis[row];
      size_t o = (size_t)row * 64 + lo;
#pragma unroll
      for (int ct = 0; ct < 4; ++ct) {
        float o0 = acc[ct][reg] + bv[ct];
        float o1 = acc[ct + 4][reg];
        float o2 = acc[ct + 8][reg];
        A02bf[o + ct * 16] = f2bf(o0 - o2);
        Y1bf[o + ct * 16] = f2bf(o1);
        Y2bf[o + ct * 16] = f2bf(dn * o2);
      }
    }
  }
}

__device__ __forceinline__ void stage_wT(unsigned short* wT,
                                         const float* __restrict__ W, int tid) {
  for (int i4 = tid; i4 < 3072; i4 += 512) {
    int k3 = i4 >> 10, rem = i4 & 1023;
    int d = rem >> 4, h4 = rem & 15;
    float4 v = ((const float4*)W)[i4];
    int colb = k3 * 64 + h4 * 4;
    wT[(colb + 0) * 64 + (d ^ swz(colb + 0))] = f2bf(v.x);
    wT[(colb + 1) * 64 + (d ^ swz(colb + 1))] = f2bf(v.y);
    wT[(colb + 2) * 64 + (d ^ swz(colb + 2))] = f2bf(v.z);
    wT[(colb + 3) * 64 + (d ^ swz(colb + 3))] = f2bf(v.w);
  }
}

__device__ __forceinline__ void gemm192_l0_body(unsigned short* x16, unsigned short* wT,
                                                int bid,
                                                const float* __restrict__ X,
                                                const float* __restrict__ W,
                                                const float* __restrict__ bias,
                                                const float* __restrict__ dis,
                                                unsigned short* __restrict__ A02bf,
                                                unsigned short* __restrict__ Y1bf,
                                                unsigned short* __restrict__ Y2bf,
                                                int N) {
  int tid = threadIdx.x;
  stage_wT(wT, W, tid);
  int rowbase = bid * 128;
  for (int i4 = tid; i4 < 2048; i4 += 512) {
    int r = i4 >> 4, c4 = i4 & 15;
    int row = rowbase + r;
    float4 v = (row < N) ? ntload4(X + (size_t)row * 64 + c4 * 4)
                         : make_float4(0.f, 0.f, 0.f, 0.f);
    us4 pk;
    pk.x = f2bf(v.x); pk.y = f2bf(v.y); pk.z = f2bf(v.z); pk.w = f2bf(v.w);
    *(us4*)&x16[r * 64 + ((c4 * 4) ^ swz(r))] = pk;
  }
  __syncthreads();
  mfma192_tail(x16, wT, rowbase, tid, bias, dis, A02bf, Y1bf, Y2bf, N);
}

// ---------- fused A: gemmsc | count+slot | sentinel | poolinit --------------
// Count role records eslot[e] = within-row slot (atomic return). 1.6M atomics
// at the measured ~8/cycle device atomic ceiling => ~84us floor for this role.
__global__ __launch_bounds__(512) void k_fused_a(const float* __restrict__ X,
                                                 const float* __restrict__ W,
                                                 const float* __restrict__ bias,
                                                 unsigned short* __restrict__ Sbf,
                                                 const int* __restrict__ row,
                                                 int* __restrict__ cnt,
                                                 int* __restrict__ eslot,
                                                 unsigned short* __restrict__ Y2bf,
                                                 unsigned short* __restrict__ Vbf,
                                                 unsigned* __restrict__ pooled,
                                                 int N, int E, int NBG, int NC,
                                                 int npool, int q) {
  __shared__ unsigned short wTsc[64 * 64];   // 8 KB
  __shared__ unsigned short x16a[128 * 64];  // 16 KB
  int bid = blockIdx.x;
  bool isg = (bid % q == 0) && (bid / q < NBG);
  if (isg) {
    gemmsc_body(wTsc, x16a, bid / q, X, W, bias, Sbf, N);
  } else {
    int before = min((bid + q - 1) / q, NBG);
    int oi = bid - before;
    if (oi < NC) {
      int e0 = oi * 2048 + threadIdx.x;
      int r[4], idx[4];
#pragma unroll
      for (int k = 0; k < 4; ++k) {
        int e = e0 + k * 512;
        if (e < E) r[k] = row[e];
      }
#pragma unroll
      for (int k = 0; k < 4; ++k) {
        int e = e0 + k * 512;
        if (e < E) idx[k] = atomicAdd(&cnt[r[k]], 1);
      }
#pragma unroll
      for (int k = 0; k < 4; ++k) {
        int e = e0 + k * 512;
        if (e < E) __builtin_nontemporal_store(idx[k], &eslot[e]);
      }
    } else if (oi == NC) {
      if (threadIdx.x < 64) {
        Y2bf[(size_t)N * 64 + threadIdx.x] = 0;
        Vbf[(size_t)N * 64 + threadIdx.x] = 0;
      }
    } else {
      int i = (oi - NC - 1) * 512 + threadIdx.x;
      if (i < npool) pooled[i] = 0x007FFFFFu;  // key(-inf)
    }
  }
}

// ---------- fused B: gemm192(l0, MFMA) | atomic-free fill ------------------
__global__ __launch_bounds__(512) void k_fused_b(const float* __restrict__ X,
                                                 const float* __restrict__ W,
                                                 const float* __restrict__ bias,
                                                 const float* __restrict__ dis,
                                                 unsigned short* __restrict__ A02bf,
                                                 unsigned short* __restrict__ Y1bf,
                                                 unsigned short* __restrict__ Y2bf,
                                                 const int* __restrict__ row,
                                                 const int* __restrict__ col,
                                                 const int* __restrict__ rowptr,
                                                 const int* __restrict__ eslot,
                                                 int* __restrict__ ccol,
                                                 int N, int E, int NBG, int q) {
  __shared__ unsigned short x16b[128 * 64];  // 16 KB
  __shared__ unsigned short wTb[192 * 64];   // 24 KB
  int bid = blockIdx.x;
  bool isg = (bid % q == 0) && (bid / q < NBG);
  if (isg) {
    gemm192_l0_body(x16b, wTb, bid / q, X, W, bias, dis, A02bf, Y1bf, Y2bf, N);
  } else {
    int before = min((bid + q - 1) / q, NBG);
    int oi = bid - before;
    int e0 = oi * 2048 + threadIdx.x;
    int r[4], c[4], sl[4], base[4];
#pragma unroll
    for (int k = 0; k < 4; ++k) {
      int e = e0 + k * 512;
      if (e < E) { r[k] = row[e]; c[k] = col[e]; sl[k] = eslot[e]; }
    }
#pragma unroll
    for (int k = 0; k < 4; ++k) {
      int e = e0 + k * 512;
      if (e < E) base[k] = rowptr[r[k]];
    }
#pragma unroll
    for (int k = 0; k < 4; ++k) {
      int e = e0 + k * 512;
      if (e < E) ccol[base[k] + sl[k]] = c[k];
    }
  }
}

// ---------- layer GEMM (l>=1): MFMA, bf16 input + in-block BN ---------------
__global__ __launch_bounds__(512) void k_gemm192(
    const unsigned short* __restrict__ Cbf,
    const float* __restrict__ sums, const float* __restrict__ sumsq,
    const float* __restrict__ g, const float* __restrict__ be,
    const float* __restrict__ W, const float* __restrict__ bias,
    const float* __restrict__ dis,
    unsigned short* __restrict__ A02bf, unsigned short* __restrict__ Y1bf,
    unsigned short* __restrict__ Y2bf, int N) {
  __shared__ unsigned short x16[128 * 64];
  __shared__ unsigned short wT[192 * 64];
  int bid = blockIdx.x;
  int tid = threadIdx.x;

  int cb = (tid & 15) * 4;
  float inv_n = 1.0f / (float)N;
  float scv[4], shv[4];
#pragma unroll
  for (int k = 0; k < 4; ++k) {
    float mu = sums[cb + k] * inv_n;
    float var = sumsq[cb + k] * inv_n - mu * mu;
    float sc = g[cb + k] * rsqrtf(var + 1e-5f);
    scv[k] = sc;
    shv[k] = be[cb + k] - mu * sc;
  }

  stage_wT(wT, W, tid);

  int rowbase = bid * 128;
  for (int i4 = tid; i4 < 2048; i4 += 512) {
    int r = i4 >> 4, c4 = i4 & 15;
    int row = rowbase + r;
    float vx, vy, vz, vw;
    if (row < N) {
      unsigned long long u =
          *(const unsigned long long*)(Cbf + (size_t)row * 64 + c4 * 4);
      vx = bf2f((unsigned short)(u & 0xffffu));
      vy = bf2f((unsigned short)((u >> 16) & 0xffffu));
      vz = bf2f((unsigned short)((u >> 32) & 0xffffu));
      vw = bf2f((unsigned short)(u >> 48));
    } else {
      vx = vy = vz = vw = 0.f;
    }
    float a = vx * scv[0] + shv[0];
    float b = vy * scv[1] + shv[1];
    float c = vz * scv[2] + shv[2];
    float d = vw * scv[3] + shv[3];
    a = (a > 0.f) ? a : 0.01f * a;
    b = (b > 0.f) ? b : 0.01f * b;
    c = (c > 0.f) ? c : 0.01f * c;
    d = (d > 0.f) ? d : 0.01f * d;
    us4 pk;
    pk.x = f2bf(a); pk.y = f2bf(b); pk.z = f2bf(c); pk.w = f2bf(d);
    *(us4*)&x16[r * 64 + ((c4 * 4) ^ swz(r))] = pk;
  }
  __syncthreads();

  mfma192_tail(x16, wT, rowbase, tid, bias, dis, A02bf, Y1bf, Y2bf, N);
}

// ---------- prop v12: v8 quartet core + STATIC contiguous row ranges -------
// Round-10 falsified dynamic stealing (single-counter serialization: 388us,
// VALU 5%, Occ 90%). This keeps v8's proven pipeline but assigns each wave a
// CONTIGUOUS block of K=ceil(N/nwaves) rows (no atomics): rowptr/ccol/inA/out
// streams become sequential per wave (strided v8 paid a full 128B line per
// row for rowptr+ccol; ~19MB/pass saved), and rowptr[n+1]==end chains free.
// Imbalance of a 13-row Poisson sum is +-7% — acceptable.
// Per 16-col window: lanes 0-15 load ccol, shfl broadcast; quartet dwordx2
// gathers (4 rows / 512B per instr). Merge via shfl_xor(16,32).
// MODE 1: Vbf[n] = bf16( dis[n]*(Y1[n] - 2*dis[n]*acc) ); zeroes stats
// MODE 2: Cbf[n] = bf16( A02[n] - dis[n]*acc )  (+ fused BN stats)
__device__ __forceinline__ void gather4(int cw, int qtr, int s,
                                        const unsigned long long* z64, float* a) {
#pragma unroll
  for (int u = 0; u < 4; ++u) {
    int c = __shfl(cw, 4 * u + qtr, 64);  // quarter q gets col 4u+q
    unsigned long long zv = z64[(size_t)c * 16 + s];
    unsigned d0 = (unsigned)zv, d1 = (unsigned)(zv >> 32);
    a[0] += __uint_as_float(d0 << 16);
    a[1] += __uint_as_float(d0 & 0xFFFF0000u);
    a[2] += __uint_as_float(d1 << 16);
    a[3] += __uint_as_float(d1 & 0xFFFF0000u);
  }
}

template <int MODE>
__global__ __launch_bounds__(256) void k_prop4(const int* __restrict__ rowptr,
                                               const int* __restrict__ ccol,
                                               const float* __restrict__ dis,
                                               const unsigned short* __restrict__ zbf,
                                               const unsigned short* __restrict__ inAbf,
                                               unsigned short* __restrict__ outbf,
                                               float* __restrict__ sums,
                                               float* __restrict__ sumsq,
                                               float* __restrict__ zstats,
                                               int N, int nwaves) {
  if (MODE == 1 && blockIdx.x == 0 && threadIdx.x < 128) zstats[threadIdx.x] = 0.f;
  int gw = blockIdx.x * 4 + (threadIdx.x >> 6);
  int lane = threadIdx.x & 63;
  int wid = threadIdx.x >> 6;
  int qtr = lane >> 4;  // quarter 0..3: handles neighbor indices 4u+qtr
  int s = lane & 15;    // sub-lane: owns channels 4s..4s+3 (8 B of a row)
  const unsigned long long* z64 = (const unsigned long long*)zbf;
  const unsigned long long* inA64 = (const unsigned long long*)inAbf;
  unsigned long long* out64 = (unsigned long long*)outbf;
  float st[4] = {0.f, 0.f, 0.f, 0.f}, st2[4] = {0.f, 0.f, 0.f, 0.f};

  int K = (N + nwaves - 1) / nwaves;   // contiguous rows per wave
  int n = gw * K;
  int nend = min(n + K, N);

  int beg = 0, end = 0, cl = 0;
  if (n < nend) {
    beg = rowptr[n];
    end = rowptr[n + 1];
    cl = ccol[beg + s];  // ccol padded by 64 -> safe
  }
  while (n < nend) {
    int nn = n + 1;
    int endn = 0;
    if (nn < nend) endn = rowptr[nn + 1];  // begn == end (contiguous rows)
    float dn = dis[n];  // hoisted: overlaps gathers
    size_t o = (size_t)n * 16 + s;
    unsigned long long av = 0;
    if (qtr == 0) av = inA64[o];  // hoisted: overlaps gathers
    float a[4] = {0.f, 0.f, 0.f, 0.f};
    {  // window 0 from prefetched cl
      int c16 = (beg + s < end) ? cl : N;  // sentinel row N is zeroed
      gather4(c16, qtr, s, z64, a);
    }
    for (int j = beg + 16; j < end; j += 16) {
      int jj = j + s;
      int c = ccol[jj];
      c = (jj < end) ? c : N;
      gather4(c, qtr, s, z64, a);
    }
    int cln = 0;
    if (nn < nend) cln = ccol[end + s];  // prefetch: overlaps merge+epilogue
    // merge quarter partials: every lane ends with the full neighbor sum
#pragma unroll
    for (int k = 0; k < 4; ++k) {
      a[k] += __shfl_xor(a[k], 16, 64);
      a[k] += __shfl_xor(a[k], 32, 64);
    }
    if (qtr == 0) {
      unsigned b0 = (unsigned)av, b1 = (unsigned)(av >> 32);
      float x0 = __uint_as_float(b0 << 16);
      float x1 = __uint_as_float(b0 & 0xFFFF0000u);
      float x2 = __uint_as_float(b1 << 16);
      float x3 = __uint_as_float(b1 & 0xFFFF0000u);
      if (MODE == 1) {
        float v0 = dn * (x0 - 2.f * dn * a[0]);
        float v1 = dn * (x1 - 2.f * dn * a[1]);
        float v2 = dn * (x2 - 2.f * dn * a[2]);
        float v3 = dn * (x3 - 2.f * dn * a[3]);
        unsigned lo = (unsigned)f2bf(v0) | ((unsigned)f2bf(v1) << 16);
        unsigned hi = (unsigned)f2bf(v2) | ((unsigned)f2bf(v3) << 16);
        out64[o] = (unsigned long long)lo | ((unsigned long long)hi << 32);
      } else {
        float v0 = x0 - dn * a[0];
        float v1 = x1 - dn * a[1];
        float v2 = x2 - dn * a[2];
        float v3 = x3 - dn * a[3];
        unsigned lo = (unsigned)f2bf(v0) | ((unsigned)f2bf(v1) << 16);
        unsigned hi = (unsigned)f2bf(v2) | ((unsigned)f2bf(v3) << 16);
        out64[o] = (unsigned long long)lo | ((unsigned long long)hi << 32);
        st[0] += v0; st2[0] = fmaf(v0, v0, st2[0]);
        st[1] += v1; st2[1] = fmaf(v1, v1, st2[1]);
        st[2] += v2; st2[2] = fmaf(v2, v2, st2[2]);
        st[3] += v3; st2[3] = fmaf(v3, v3, st2[3]);
      }
    }
    n = nn; beg = end; end = endn; cl = cln;
  }
  if (MODE == 2) {
    __shared__ float red[2][4][64];
    if (qtr == 0) {
#pragma unroll
      for (int k = 0; k < 4; ++k) {
        red[0][wid][4 * s + k] = st[k];
        red[1][wid][4 * s + k] = st2[k];
      }
    }
    __syncthreads();
    if (wid == 0) {
      float a = red[0][0][lane] + red[0][1][lane] + red[0][2][lane] + red[0][3][lane];
      float b = red[1][0][lane] + red[1][1][lane] + red[1][2][lane] + red[1][3][lane];
      atomicAdd(&sums[lane], a);
      atomicAdd(&sumsq[lane], b);
    }
  }
}

// fused: h = lrelu(bn(Cbf)) + Sbf; segment-max into pooled (coefs in-block)
__global__ void k_bnpool(const unsigned short* __restrict__ Cbf,
                         const float* __restrict__ sums, const float* __restrict__ sumsq,
                         const float* __restrict__ g, const float* __restrict__ be,
                         const unsigned short* __restrict__ Sbf,
                         const int* __restrict__ batch,
                         unsigned* __restrict__ pooled, int N) {
  __shared__ float sc_s[64], sh_s[64];
  if (threadIdx.x < 64) {
    int h = threadIdx.x;
    float inv_n = 1.0f / (float)N;
    float mu = sums[h] * inv_n;
    float var = sumsq[h] * inv_n - mu * mu;
    float sc = g[h] * rsqrtf(var + 1e-5f);
    sc_s[h] = sc;
    sh_s[h] = be[h] - mu * sc;
  }
  __syncthreads();
  int t = threadIdx.x;
  int h = t & 63;
  int rsub = t >> 6;
  int base = blockIdx.x * 64;
  float sc = sc_s[h], sh = sh_s[h];
  int cur_g = -1;
  unsigned best = 0;
  for (int i = 0; i < 16; ++i) {
    int n = base + rsub + 4 * i;
    if (n >= N) break;
    int gidx = batch[n];
    size_t o = (size_t)n * 64 + h;
    float a = bf2f(__builtin_nontemporal_load(&Cbf[o])) * sc + sh;
    a = (a > 0.f) ? a : 0.01f * a;
    a += bf2f(__builtin_nontemporal_load(&Sbf[o]));
    unsigned k = f2key(a);
    if (gidx != cur_g) {
      if (cur_g >= 0) atomicMax(&pooled[cur_g * 64 + h], best);
      cur_g = gidx;
      best = k;
    } else {
      best = max(best, k);
    }
  }
  if (cur_g >= 0) atomicMax(&pooled[cur_g * 64 + h], best);
}

__global__ void k_final(const unsigned* __restrict__ pooled, const float* __restrict__ w_lin,
                        const float* __restrict__ b_lin, float* __restrict__ out) {
  int g = blockIdx.x;
  int h = threadIdx.x;
  float v = key2f(pooled[g * 64 + h]) * w_lin[h];
  for (int off = 32; off > 0; off >>= 1) v += __shfl_down(v, off, 64);
  if (h == 0) out[g] = v + b_lin[0];
}

extern "C" void kernel_launch(void* const* d_in, const int* in_sizes, int n_in,
                              void* d_out, int out_size, void* d_ws, size_t ws_size,
                              hipStream_t stream) {
  const float* x = (const float*)d_in[0];
  const int* ei = (const int*)d_in[1];
  const int* batch = (const int*)d_in[2];
  const float* w1 = (const float*)d_in[3];
  const float* b1 = (const float*)d_in[4];
  const float* w2 = (const float*)d_in[5];
  const float* b2 = (const float*)d_in[6];
  const float* w3 = (const float*)d_in[7];
  const float* b3 = (const float*)d_in[8];
  const float* g1 = (const float*)d_in[9];
  const float* be1 = (const float*)d_in[10];
  const float* g2 = (const float*)d_in[11];
  const float* be2 = (const float*)d_in[12];
  const float* g3 = (const float*)d_in[13];
  const float* be3 = (const float*)d_in[14];
  const float* w_sc = (const float*)d_in[15];
  const float* b_sc = (const float*)d_in[16];
  const float* w_lin = (const float*)d_in[17];
  const float* b_lin = (const float*)d_in[18];

  int N = in_sizes[0] / 64;
  int E = in_sizes[1] / 2;
  int G = out_size;
  const int* row = ei;
  const int* col = ei + E;

  char* p = (char*)d_ws;
  auto carve = [&](size_t bytes) -> void* {
    void* r = (void*)p;
    p += (bytes + 255) & ~(size_t)255;
    return r;
  };
  int* cnt = (int*)carve((size_t)N * 4);
  float* dis = (float*)carve((size_t)N * 4);
  int* rowptr = (int*)carve((size_t)(N + 1) * 4);
  int* eslot = (int*)carve((size_t)E * 4);
  int* incl = (int*)carve((size_t)N * 4);
  int* bsum = (int*)carve(1024);
  int* bex = (int*)carve(1024);
  int* ccol = (int*)carve((size_t)(E + 64) * 4);   // +64 pad for window over-read
  unsigned short* Sbf = (unsigned short*)carve((size_t)N * 64 * 2);
  unsigned short* A02bf = (unsigned short*)carve((size_t)N * 64 * 2);
  unsigned short* Y1bf = (unsigned short*)carve((size_t)N * 64 * 2);
  unsigned short* Y2bf = (unsigned short*)carve((size_t)(N + 1) * 64 * 2);  // row N = 0
  unsigned short* Vbf = (unsigned short*)carve((size_t)(N + 1) * 64 * 2);   // row N = 0
  unsigned short* Cbf = (unsigned short*)carve((size_t)N * 64 * 2);
  float* stats = (float*)carve(256 * 4);  // sums|sumsq
  unsigned* pooled = (unsigned*)carve((size_t)G * 64 * 4);

  int NBG = DIV_UP(N, 128);
  int NC = DIV_UP(E, 2048);
  int npool = G * 64;
  int NPI = DIV_UP(npool, 512);

  int TA = NBG + NC + 1 + NPI;
  int qa = (NBG > 1) ? (TA - 1) / (NBG - 1) : 1;
  if (qa < 1) qa = 1;
  int TB = NBG + NC;
  int qb = (NBG > 1) ? (TB - 1) / (NBG - 1) : 1;
  if (qb < 1) qb = 1;

  // ---- graph build + overlapped independent compute ----
  hipMemsetAsync(cnt, 0, (size_t)N * 4, stream);
  // A: gemmsc || degree count+slot || sentinel zero || poolinit
  k_fused_a<<<TA, 512, 0, stream>>>(x, w_sc, b_sc, Sbf, row, cnt, eslot,
                                    Y2bf, Vbf, pooled, N, E, NBG, NC, npool, qa);
  int nb = DIV_UP(N, 1024);
  k_scan1<<<nb, 1024, 0, stream>>>(cnt, incl, bsum, N);
  k_scan2<<<1, 128, 0, stream>>>(bsum, bex, nb);
  k_scan3<<<DIV_UP(N, 256), 256, 0, stream>>>(incl, cnt, bex, rowptr, dis, N, E);
  // B: gemm192(layer0) || atomic-free CSR fill
  k_fused_b<<<TB, 512, 0, stream>>>(x, w1, b1, dis, A02bf, Y1bf, Y2bf,
                                    row, col, rowptr, eslot, ccol, N, E, NBG, qb);

  const float* Ws[3] = {w1, w2, w3};
  const float* bs[3] = {b1, b2, b3};
  const float* gs[3] = {g1, g2, g3};
  const float* bes[3] = {be1, be2, be3};

  const int PBLK = 2048;      // persistent blocks, 4 waves each (all resident)
  const int NWAVE = PBLK * 4;
  for (int l = 0; l < 3; ++l) {
    if (l > 0)
      k_gemm192<<<NBG, 512, 0, stream>>>(Cbf, stats, stats + 64, gs[l - 1], bes[l - 1],
                                         Ws[l], bs[l], dis, A02bf, Y1bf, Y2bf, N);
    // Vbf = bf16( dis * (Y1 + 2*P*Y2) )   (also zeroes stats)
    k_prop4<1><<<PBLK, 256, 0, stream>>>(rowptr, ccol, dis, Y2bf, Y1bf,
                                         Vbf, nullptr, nullptr, stats, N, NWAVE);
    // Cbf = bf16( (Y0 - Y2) + P*V )  (+ fused BN stats)
    k_prop4<2><<<PBLK, 256, 0, stream>>>(rowptr, ccol, dis, Vbf, A02bf,
                                         Cbf, stats, stats + 64, nullptr, N, NWAVE);
  }

  k_bnpool<<<DIV_UP(N, 64), 256, 0, stream>>>(Cbf, stats, stats + 64, g3, be3,
                                              Sbf, batch, pooled, N);
  k_final<<<G, 64, 0, stream>>>(pooled, w_lin, b_lin, (float*)d_out);
}